// Round 1
// baseline (8181.276 us; speedup 1.0000x reference)
//
#include <hip/hip_runtime.h>
#include <stdint.h>

typedef __attribute__((ext_vector_type(8))) short short8;
typedef __attribute__((ext_vector_type(4))) float f32x4;
typedef __attribute__((ext_vector_type(4))) unsigned int u32x4;

#define TSTEPS 512
#define HD 1024
#define ID 256
#define OD 256

__device__ __forceinline__ ushort f2bf(float f) {
  uint32_t x = __float_as_uint(f);
  return (ushort)((x + 0x7fffu + ((x >> 16) & 1u)) >> 16);
}
__device__ __forceinline__ float bf2f(ushort u) {
  return __uint_as_float(((uint32_t)u) << 16);
}
__device__ __forceinline__ float sigm(float v) {
  return 1.0f / (1.0f + __expf(-v));
}

// Persistent LSTM kernel.
// grid = 256 WGs x 256 threads. group g = (bidx&7)>>1 (2 XCD residues per group),
// wg-in-group = ((bidx>>3)<<1)|(bidx&1) in 0..63.
// Group g owns batches [16g,16g+16). WG owns hidden cols [wg*16, wg*16+16) x 4 gates.
// Wave w of the WG handles gate w (g,i,f,o), 16 rows of Wh/Wx held in registers as
// bf16 MFMA B-fragments. h double-buffered in ws (bf16, XOR-swizzled 16B chunks).
__global__ __launch_bounds__(256, 1) void lstm_persist(
    const float* __restrict__ x,
    const float* __restrict__ Wgx, const float* __restrict__ bgx, const float* __restrict__ Wgh,
    const float* __restrict__ Wix, const float* __restrict__ bix, const float* __restrict__ Wih,
    const float* __restrict__ Wfx, const float* __restrict__ bfx, const float* __restrict__ Wfh,
    const float* __restrict__ Wox, const float* __restrict__ boxx, const float* __restrict__ Woh,
    const float* __restrict__ Wout, const float* __restrict__ bout,
    float* __restrict__ out, uint8_t* __restrict__ ws)
{
  __shared__ alignas(16) uint8_t h_lds[32768];  // [16 rows][1024 bf16], swizzled chunks
  __shared__ alignas(16) uint8_t x_lds[8192];   // [16 rows][256 bf16], swizzled chunks
  __shared__ float gate_lds[4 * 256];           // 4 gates x [16b x 16j] fp32
  __shared__ float bias_lds[4 * 16];

  const int tid  = threadIdx.x;
  const int lane = tid & 63;
  const int wid  = tid >> 6;
  const int bidx = blockIdx.x;
  const int g  = (bidx & 7) >> 1;
  const int wg = ((bidx >> 3) << 1) | (bidx & 1);
  const int j0 = wg * 16;     // hidden-column base for this WG
  const int b0 = g * 16;      // batch base for this group

  // ws layout: [0,4096) barriers (zeroed), [4096, 4096+2*131072) h double buffer
  uint32_t* bar_cnt  = (uint32_t*)(ws + (size_t)g * 1024);
  uint32_t* bar_flag = (uint32_t*)(ws + (size_t)g * 1024 + 512);
  uint8_t* hbuf = ws + 4096;
  uint8_t* htile[2];
  htile[0] = hbuf + (size_t)g * 32768;
  htile[1] = hbuf + 131072 + (size_t)g * 32768;

  // per-wave gate selection (wave-uniform)
  const float* Wh = (wid == 0) ? Wgh : (wid == 1) ? Wih : (wid == 2) ? Wfh : Woh;
  const float* Wx = (wid == 0) ? Wgx : (wid == 1) ? Wix : (wid == 2) ? Wfx : Wox;

  // biases into LDS (survive; LDS is not invalidated by acquire fences)
  if (tid < 64) {
    int gg = tid >> 4, jj = tid & 15;
    const float* bp = (gg == 0) ? bgx : (gg == 1) ? bix : (gg == 2) ? bfx : boxx;
    bias_lds[gg * 16 + jj] = bp[j0 + jj];
  }

  // ---- load weight B-fragments into registers (one-time) ----
  // B-frag convention: lane holds B[k][n] with n = lane&15 (W row j0+n),
  // k = kk*32 + (lane>>4)*8 + e. Same (block,e)->k mapping used for A => any
  // internal K-permutation cancels.
  const int r16 = lane & 15;
  const int kq  = lane >> 4;
  short8 whf[32];
  short8 wxf[8];
  {
    const float* base = Wh + (size_t)(j0 + r16) * HD + kq * 8;
    #pragma unroll
    for (int kk = 0; kk < 32; kk++) {
      f32x4 lo = *(const f32x4*)(base + kk * 32);
      f32x4 hi = *(const f32x4*)(base + kk * 32 + 4);
      short8 w;
      w[0] = (short)f2bf(lo[0]); w[1] = (short)f2bf(lo[1]);
      w[2] = (short)f2bf(lo[2]); w[3] = (short)f2bf(lo[3]);
      w[4] = (short)f2bf(hi[0]); w[5] = (short)f2bf(hi[1]);
      w[6] = (short)f2bf(hi[2]); w[7] = (short)f2bf(hi[3]);
      whf[kk] = w;
    }
    const float* xb = Wx + (size_t)(j0 + r16) * ID + kq * 8;
    #pragma unroll
    for (int kk = 0; kk < 8; kk++) {
      f32x4 lo = *(const f32x4*)(xb + kk * 32);
      f32x4 hi = *(const f32x4*)(xb + kk * 32 + 4);
      short8 w;
      w[0] = (short)f2bf(lo[0]); w[1] = (short)f2bf(lo[1]);
      w[2] = (short)f2bf(lo[2]); w[3] = (short)f2bf(lo[3]);
      w[4] = (short)f2bf(hi[0]); w[5] = (short)f2bf(hi[1]);
      w[6] = (short)f2bf(hi[2]); w[7] = (short)f2bf(hi[3]);
      wxf[kk] = w;
    }
  }

  // stage helpers. h tile: [16][2048B] rows; 16B chunk c at row r stored at chunk c^(r&7).
  auto stage_h = [&](const uint8_t* src) {
    #pragma unroll
    for (int i = 0; i < 8; i++) {
      *(u32x4*)(h_lds + i * 4096 + tid * 16) = *(const u32x4*)(src + i * 4096 + tid * 16);
    }
  };
  auto stage_x = [&](int t) {
    int b = tid >> 4, seg = tid & 15;
    const float* xp = x + ((size_t)(b0 + b) * TSTEPS + t) * ID + seg * 16;
    float v[16];
    #pragma unroll
    for (int q = 0; q < 4; q++) {
      f32x4 f = *(const f32x4*)(xp + q * 4);
      v[q * 4 + 0] = f[0]; v[q * 4 + 1] = f[1];
      v[q * 4 + 2] = f[2]; v[q * 4 + 3] = f[3];
    }
    u32x4 c0, c1;
    #pragma unroll
    for (int q = 0; q < 4; q++) {
      c0[q] = (uint32_t)f2bf(v[2 * q]) | ((uint32_t)f2bf(v[2 * q + 1]) << 16);
      c1[q] = (uint32_t)f2bf(v[8 + 2 * q]) | ((uint32_t)f2bf(v[8 + 2 * q + 1]) << 16);
    }
    int row = b * 512;
    *(u32x4*)(x_lds + row + (((seg * 2)     ^ (b & 7)) * 16)) = c0;
    *(u32x4*)(x_lds + row + (((seg * 2 + 1) ^ (b & 7)) * 16)) = c1;
  };

  float c_reg = 0.0f;  // c for (b = tid>>4, j = j0 + (tid&15))
  int par = 0;

  stage_h(htile[0]);   // zeros (memset)
  stage_x(0);
  __syncthreads();

  for (int t = 0; t < TSTEPS; t++) {
    // ---- 4 gate GEMMs: acc[b][j] = sum_k h[b][k] Wh[j][k] + sum_k x[b][k] Wx[j][k]
    f32x4 acc[4];
    #pragma unroll
    for (int q = 0; q < 4; q++) acc[q] = (f32x4){0.f, 0.f, 0.f, 0.f};

    #pragma unroll
    for (int kk = 0; kk < 8; kk++) {
      int chunk = (kk * 4 + kq) ^ (r16 & 7);
      short8 a = *(const short8*)(x_lds + r16 * 512 + chunk * 16);
      acc[kk & 3] = __builtin_amdgcn_mfma_f32_16x16x32_bf16(a, wxf[kk], acc[kk & 3], 0, 0, 0);
    }
    #pragma unroll
    for (int kk = 0; kk < 32; kk++) {
      int chunk = (kk * 4 + kq) ^ (r16 & 7);
      short8 a = *(const short8*)(h_lds + r16 * 2048 + chunk * 16);
      acc[kk & 3] = __builtin_amdgcn_mfma_f32_16x16x32_bf16(a, whf[kk], acc[kk & 3], 0, 0, 0);
    }
    f32x4 accv = (acc[0] + acc[1]) + (acc[2] + acc[3]);

    // ---- cross-wave gate exchange (D layout: col=lane&15=j, row=(lane>>4)*4+r=batch)
    #pragma unroll
    for (int r = 0; r < 4; r++)
      gate_lds[wid * 256 + (kq * 4 + r) * 16 + r16] = accv[r];
    __syncthreads();

    // ---- elementwise LSTM cell (fp32), one (b,j) per thread
    {
      int b = tid >> 4, jl = tid & 15;
      int idx = b * 16 + jl;
      float gv = tanhf(gate_lds[0 * 256 + idx] + bias_lds[0 * 16 + jl]);
      float iv = sigm (gate_lds[1 * 256 + idx] + bias_lds[1 * 16 + jl]);
      float fv = sigm (gate_lds[2 * 256 + idx] + bias_lds[2 * 16 + jl]);
      float ov = sigm (gate_lds[3 * 256 + idx] + bias_lds[3 * 16 + jl]);
      c_reg = gv * iv + c_reg * fv;
      float hv = tanhf(c_reg) * ov;
      int j = j0 + jl;
      int swz = (((j >> 3) ^ (b & 7)) << 4) | ((j & 7) << 1);
      *(ushort*)(htile[par ^ 1] + b * 2048 + swz) = f2bf(hv);
    }
    __syncthreads();  // all h' stores issued before the fence

    // ---- group barrier (64 WGs), monotonic counter + flag
    if (tid == 0) {
      __threadfence();
      uint32_t tgt = (uint32_t)(t + 1);
      uint32_t old = __hip_atomic_fetch_add(bar_cnt, 1u, __ATOMIC_ACQ_REL, __HIP_MEMORY_SCOPE_AGENT);
      if (old == 64u * tgt - 1u) {
        __hip_atomic_store(bar_flag, tgt, __ATOMIC_RELEASE, __HIP_MEMORY_SCOPE_AGENT);
      } else {
        while (__hip_atomic_load(bar_flag, __ATOMIC_RELAXED, __HIP_MEMORY_SCOPE_AGENT) < tgt)
          __builtin_amdgcn_s_sleep(2);
        (void)__hip_atomic_load(bar_flag, __ATOMIC_ACQUIRE, __HIP_MEMORY_SCOPE_AGENT);
      }
    }
    __syncthreads();

    par ^= 1;
    stage_h(htile[par]);
    stage_x((t + 1 < TSTEPS) ? (t + 1) : 0);
    __syncthreads();
  }

  // ---- epilogue: out[b, o] = h[b,:] . Wout[o,:] + bout[o], group-local
  {
    const uint8_t* ht = htile[par];  // h[T]
    int b = tid >> 4, rem = tid & 15, ol = rem >> 2, kq4 = rem & 3;
    int o = wg * 4 + ol;
    const float* wr = Wout + (size_t)o * HD;
    const uint8_t* hrow = ht + b * 2048;
    float sum = 0.0f;
    for (int k = kq4 * 256; k < kq4 * 256 + 256; k += 8) {
      int chunk = ((k >> 3) ^ (b & 7));
      const ushort* hp = (const ushort*)(hrow + chunk * 16);
      #pragma unroll
      for (int e = 0; e < 8; e++) sum += bf2f(hp[e]) * wr[k + e];
    }
    float* red = gate_lds;
    red[tid] = sum;
    __syncthreads();
    if (kq4 == 0) {
      float s = red[tid] + red[tid + 1] + red[tid + 2] + red[tid + 3];
      out[(size_t)(b0 + b) * OD + o] = s + bout[o];
    }
  }
}

extern "C" void kernel_launch(void* const* d_in, const int* in_sizes, int n_in,
                              void* d_out, int out_size, void* d_ws, size_t ws_size,
                              hipStream_t stream) {
  // zero barrier area + h buffer 0 (initial h state)
  hipMemsetAsync(d_ws, 0, 4096 + 131072, stream);

  const float* x    = (const float*)d_in[0];
  const float* Wgx  = (const float*)d_in[1];
  const float* bgx  = (const float*)d_in[2];
  const float* Wgh  = (const float*)d_in[3];
  const float* Wix  = (const float*)d_in[4];
  const float* bix  = (const float*)d_in[5];
  const float* Wih  = (const float*)d_in[6];
  const float* Wfx  = (const float*)d_in[7];
  const float* bfx  = (const float*)d_in[8];
  const float* Wfh  = (const float*)d_in[9];
  const float* Wox  = (const float*)d_in[10];
  const float* boxx = (const float*)d_in[11];
  const float* Woh  = (const float*)d_in[12];
  const float* Wout = (const float*)d_in[13];
  const float* bout = (const float*)d_in[14];

  lstm_persist<<<dim3(256), dim3(256), 0, stream>>>(
      x, Wgx, bgx, Wgh, Wix, bix, Wih, Wfx, bfx, Wfh, Wox, boxx, Woh,
      Wout, bout, (float*)d_out, (uint8_t*)d_ws);
}

// Round 2
// 2480.526 us; speedup vs baseline: 3.2982x; 3.2982x over previous
//
#include <hip/hip_runtime.h>
#include <stdint.h>

typedef __attribute__((ext_vector_type(8))) short short8;
typedef __attribute__((ext_vector_type(4))) float f32x4;
typedef __attribute__((ext_vector_type(4))) unsigned int u32x4;

#define TSTEPS 512
#define HD 1024
#define ID 256
#define OD 256

static __device__ __forceinline__ ushort f2bf(float f) {
  uint32_t x = __float_as_uint(f);
  return (ushort)((x + 0x7fffu + ((x >> 16) & 1u)) >> 16);
}
static __device__ __forceinline__ float bf2f(ushort u) {
  return __uint_as_float(((uint32_t)u) << 16);
}
static __device__ __forceinline__ float sigm(float v) {
  return 1.0f / (1.0f + __expf(-v));
}

// Persistent LSTM. 4 groups x 32 WGs x 256 threads (128 WGs total, 1/CU).
// Group g owns batches [16g, 16g+16). WG owns 32 hidden cols x 4 gates.
// Wave w = gate w; weights as register B-fragments (2 col-halves).
// Coherence: hand-rolled sc0sc1 (coherence-point) loads/stores for h tiles and
// flags -- NO agent-scope fences (no buffer_wbl2 / buffer_inv).
__global__ __launch_bounds__(256, 1) void lstm_persist(
    const float* __restrict__ x,
    const float* __restrict__ Wgx, const float* __restrict__ bgx, const float* __restrict__ Wgh,
    const float* __restrict__ Wix, const float* __restrict__ bix, const float* __restrict__ Wih,
    const float* __restrict__ Wfx, const float* __restrict__ bfx, const float* __restrict__ Wfh,
    const float* __restrict__ Wox, const float* __restrict__ boxx, const float* __restrict__ Woh,
    const float* __restrict__ Wout, const float* __restrict__ bout,
    float* __restrict__ out, uint8_t* __restrict__ ws)
{
  __shared__ alignas(16) uint8_t h_lds[32768];      // [16 b][1024 bf16], swizzled 16B chunks
  __shared__ alignas(16) uint8_t x_lds[2][8192];    // [16 b][256 bf16], swizzled
  __shared__ float gate_lds[4 * 512];               // [gate][16 b][32 j] fp32
  __shared__ float bias_lds[4 * 32];
  __shared__ float red_lds[256];

  const int tid  = threadIdx.x;
  const int lane = tid & 63;
  const int wid  = tid >> 6;
  const int bidx = blockIdx.x;
  const int g   = bidx & 3;        // group: consecutive bidx spread across XCD residues
  const int wg  = bidx >> 2;       // 0..31 within group
  const int j0w = wg * 32;
  const int b0  = g * 16;

  uint32_t* flags = (uint32_t*)(ws + (size_t)g * 1024);   // flags[0..31], monotonic step count
  uint8_t* tile[2];
  tile[0] = ws + 4096 + (size_t)g * 32768;
  tile[1] = ws + 4096 + 131072 + (size_t)g * 32768;

  const float* Wh = (wid == 0) ? Wgh : (wid == 1) ? Wih : (wid == 2) ? Wfh : Woh;
  const float* Wx = (wid == 0) ? Wgx : (wid == 1) ? Wix : (wid == 2) ? Wfx : Wox;

  if (tid < 128) {
    int gg = tid >> 5, jj = tid & 31;
    const float* bp = (gg == 0) ? bgx : (gg == 1) ? bix : (gg == 2) ? bfx : boxx;
    bias_lds[gg * 32 + jj] = bp[j0w + jj];
  }

  const int r16 = lane & 15;
  const int kq  = lane >> 4;

  // ---- weights -> register B-fragments (whole-kernel live range) ----
  // B-frag: n = lane&15 (W row j0w + c*16 + n), k = kk*32 + kq*8 + e.
  // Same (kq,e)->k convention as A-frags => HW K-permutation cancels.
  short8 whf[2][32];
  short8 wxf[2][8];
  #pragma unroll
  for (int c = 0; c < 2; c++) {
    const float* base = Wh + (size_t)(j0w + c * 16 + r16) * HD + kq * 8;
    #pragma unroll
    for (int kk = 0; kk < 32; kk++) {
      f32x4 lo = *(const f32x4*)(base + kk * 32);
      f32x4 hi = *(const f32x4*)(base + kk * 32 + 4);
      short8 w;
      w[0] = (short)f2bf(lo[0]); w[1] = (short)f2bf(lo[1]);
      w[2] = (short)f2bf(lo[2]); w[3] = (short)f2bf(lo[3]);
      w[4] = (short)f2bf(hi[0]); w[5] = (short)f2bf(hi[1]);
      w[6] = (short)f2bf(hi[2]); w[7] = (short)f2bf(hi[3]);
      whf[c][kk] = w;
    }
    const float* xb = Wx + (size_t)(j0w + c * 16 + r16) * ID + kq * 8;
    #pragma unroll
    for (int kk = 0; kk < 8; kk++) {
      f32x4 lo = *(const f32x4*)(xb + kk * 32);
      f32x4 hi = *(const f32x4*)(xb + kk * 32 + 4);
      short8 w;
      w[0] = (short)f2bf(lo[0]); w[1] = (short)f2bf(lo[1]);
      w[2] = (short)f2bf(lo[2]); w[3] = (short)f2bf(lo[3]);
      w[4] = (short)f2bf(hi[0]); w[5] = (short)f2bf(hi[1]);
      w[6] = (short)f2bf(hi[2]); w[7] = (short)f2bf(hi[3]);
      wxf[c][kk] = w;
    }
  }

  auto stage_x = [&](int t, int buf) {
    int b = tid >> 4, seg = tid & 15;
    const float* xp = x + ((size_t)(b0 + b) * TSTEPS + t) * ID + seg * 16;
    float v[16];
    #pragma unroll
    for (int q = 0; q < 4; q++) {
      f32x4 f = *(const f32x4*)(xp + q * 4);
      v[q * 4 + 0] = f[0]; v[q * 4 + 1] = f[1];
      v[q * 4 + 2] = f[2]; v[q * 4 + 3] = f[3];
    }
    u32x4 c0, c1;
    #pragma unroll
    for (int q = 0; q < 4; q++) {
      c0[q] = (uint32_t)f2bf(v[2 * q])     | ((uint32_t)f2bf(v[2 * q + 1]) << 16);
      c1[q] = (uint32_t)f2bf(v[8 + 2 * q]) | ((uint32_t)f2bf(v[8 + 2 * q + 1]) << 16);
    }
    uint8_t* row = &x_lds[buf][0] + b * 512;
    *(u32x4*)(row + (((seg * 2)     ^ (b & 7)) * 16)) = c0;
    *(u32x4*)(row + (((seg * 2 + 1) ^ (b & 7)) * 16)) = c1;
  };

  float c0f = 0.0f, c1f = 0.0f;   // c-state for (b=tid>>4, j = j0w + (tid&15)*2 + {0,1})

  stage_x(0, 0);
  __syncthreads();

  for (int t = 0; ; t++) {
    // ---- wait for h_t tile (all 32 producer flags >= t) ----
    if (t) {
      const uint32_t* fp = flags + (lane & 31);
      uint32_t fv;
      for (;;) {
        asm volatile("global_load_dword %0, %1, off sc0 sc1\n\ts_waitcnt vmcnt(0)"
                     : "=v"(fv) : "v"(fp) : "memory");
        if (__all(fv >= (uint32_t)t)) break;
        __builtin_amdgcn_s_sleep(4);
      }
    }
    // ---- stage h tile -> LDS (coherence-point reads) ----
    {
      const uint8_t* src = tile[t & 1];
      u32x4 v[8];
      #pragma unroll
      for (int i = 0; i < 8; i++) {
        asm volatile("global_load_dwordx4 %0, %1, off sc0 sc1"
                     : "=v"(v[i]) : "v"(src + i * 4096 + tid * 16) : "memory");
      }
      asm volatile("s_waitcnt vmcnt(0)" ::: "memory");
      __builtin_amdgcn_sched_barrier(0);
      #pragma unroll
      for (int i = 0; i < 8; i++)
        *(u32x4*)(h_lds + i * 4096 + tid * 16) = v[i];
    }
    __syncthreads();
    if (t == TSTEPS) break;

    // ---- gate GEMM: 80 MFMAs (2 col-halves x (8 x-kk + 32 h-kk)) ----
    f32x4 a0[4], a1[4];
    #pragma unroll
    for (int q = 0; q < 4; q++) { a0[q] = (f32x4){0.f,0.f,0.f,0.f}; a1[q] = (f32x4){0.f,0.f,0.f,0.f}; }

    const uint8_t* xl = &x_lds[t & 1][0];
    #pragma unroll
    for (int kk = 0; kk < 8; kk++) {
      int chunk = (kk * 4 + kq) ^ (r16 & 7);
      short8 a = *(const short8*)(xl + r16 * 512 + chunk * 16);
      a0[kk & 3] = __builtin_amdgcn_mfma_f32_16x16x32_bf16(a, wxf[0][kk], a0[kk & 3], 0, 0, 0);
      a1[kk & 3] = __builtin_amdgcn_mfma_f32_16x16x32_bf16(a, wxf[1][kk], a1[kk & 3], 0, 0, 0);
    }
    #pragma unroll
    for (int kk = 0; kk < 32; kk++) {
      int chunk = (kk * 4 + kq) ^ (r16 & 7);
      short8 a = *(const short8*)(h_lds + r16 * 2048 + chunk * 16);
      a0[kk & 3] = __builtin_amdgcn_mfma_f32_16x16x32_bf16(a, whf[0][kk], a0[kk & 3], 0, 0, 0);
      a1[kk & 3] = __builtin_amdgcn_mfma_f32_16x16x32_bf16(a, whf[1][kk], a1[kk & 3], 0, 0, 0);
    }
    f32x4 v0 = (a0[0] + a0[1]) + (a0[2] + a0[3]);
    f32x4 v1 = (a1[0] + a1[1]) + (a1[2] + a1[3]);

    // ---- cross-wave gate exchange (D: col=lane&15=j, row=(lane>>4)*4+r=batch) ----
    #pragma unroll
    for (int r = 0; r < 4; r++) {
      int row = kq * 4 + r;
      gate_lds[wid * 512 + row * 32 + r16]      = v0[r];
      gate_lds[wid * 512 + row * 32 + 16 + r16] = v1[r];
    }
    __syncthreads();

    // ---- elementwise cell update, 2 (b,j) per thread ----
    {
      int b = tid >> 4, jl2 = tid & 15;
      int ja = jl2 * 2, jb = ja + 1;
      float ga = tanhf(gate_lds[0 * 512 + b * 32 + ja] + bias_lds[0 * 32 + ja]);
      float ia = sigm (gate_lds[1 * 512 + b * 32 + ja] + bias_lds[1 * 32 + ja]);
      float fa = sigm (gate_lds[2 * 512 + b * 32 + ja] + bias_lds[2 * 32 + ja]);
      float oa = sigm (gate_lds[3 * 512 + b * 32 + ja] + bias_lds[3 * 32 + ja]);
      c0f = ga * ia + c0f * fa;
      float ha = tanhf(c0f) * oa;

      float gb = tanhf(gate_lds[0 * 512 + b * 32 + jb] + bias_lds[0 * 32 + jb]);
      float ib = sigm (gate_lds[1 * 512 + b * 32 + jb] + bias_lds[1 * 32 + jb]);
      float fb = sigm (gate_lds[2 * 512 + b * 32 + jb] + bias_lds[2 * 32 + jb]);
      float ob = sigm (gate_lds[3 * 512 + b * 32 + jb] + bias_lds[3 * 32 + jb]);
      c1f = gb * ib + c1f * fb;
      float hb = tanhf(c1f) * ob;

      uint32_t pv = (uint32_t)f2bf(ha) | ((uint32_t)f2bf(hb) << 16);
      int j = j0w + ja;
      int chunk = (j >> 3) ^ (b & 7);
      uint8_t* dst = tile[(t + 1) & 1] + b * 2048 + chunk * 16 + (j & 7) * 2;
      asm volatile("global_store_dword %0, %1, off sc0 sc1" :: "v"(dst), "v"(pv) : "memory");
      asm volatile("s_waitcnt vmcnt(0)" ::: "memory");   // per-wave: own stores at coherence point
    }
    __syncthreads();   // all 4 waves' stores complete

    if (tid == 0) {
      uint32_t fl = (uint32_t)(t + 1);
      asm volatile("global_store_dword %0, %1, off sc0 sc1" :: "v"(flags + wg), "v"(fl) : "memory");
    }

    // prefetch x_{t+1} (overlaps with next poll)
    int tn = (t + 1 < TSTEPS) ? (t + 1) : (TSTEPS - 1);
    stage_x(tn, (t + 1) & 1);
  }

  // ---- epilogue: out[b,o] = h_T[b,:] . Wout[o,:] + bout[o] (h_T staged in h_lds) ----
  {
    int b = tid >> 4, rem = tid & 15;
    int ol = rem >> 1, kh = rem & 1;
    int o = wg * 8 + ol;
    const float* wr = Wout + (size_t)o * HD;
    float sum = 0.0f;
    for (int k8 = kh * 64; k8 < kh * 64 + 64; k8++) {
      const ushort* hp = (const ushort*)(h_lds + b * 2048 + (k8 ^ (b & 7)) * 16);
      const float* wp = wr + k8 * 8;
      #pragma unroll
      for (int e = 0; e < 8; e++) sum += bf2f(hp[e]) * wp[e];
    }
    red_lds[tid] = sum;
    __syncthreads();
    if (kh == 0)
      out[(size_t)(b0 + b) * OD + o] = red_lds[tid] + red_lds[tid + 1] + bout[o];
  }
}

extern "C" void kernel_launch(void* const* d_in, const int* in_sizes, int n_in,
                              void* d_out, int out_size, void* d_ws, size_t ws_size,
                              hipStream_t stream) {
  // zero flags (4 KB) + h tile parity-0 (128 KB) each launch
  hipMemsetAsync(d_ws, 0, 4096 + 131072, stream);

  const float* x    = (const float*)d_in[0];
  const float* Wgx  = (const float*)d_in[1];
  const float* bgx  = (const float*)d_in[2];
  const float* Wgh  = (const float*)d_in[3];
  const float* Wix  = (const float*)d_in[4];
  const float* bix  = (const float*)d_in[5];
  const float* Wih  = (const float*)d_in[6];
  const float* Wfx  = (const float*)d_in[7];
  const float* bfx  = (const float*)d_in[8];
  const float* Wfh  = (const float*)d_in[9];
  const float* Wox  = (const float*)d_in[10];
  const float* boxx = (const float*)d_in[11];
  const float* Woh  = (const float*)d_in[12];
  const float* Wout = (const float*)d_in[13];
  const float* bout = (const float*)d_in[14];

  lstm_persist<<<dim3(128), dim3(256), 0, stream>>>(
      x, Wgx, bgx, Wgh, Wix, bix, Wih, Wfx, bfx, Wfh, Wox, boxx, Woh,
      Wout, bout, (float*)d_out, (uint8_t*)d_ws);
}